// Round 1
// baseline (184.101 us; speedup 1.0000x reference)
//
#include <hip/hip_runtime.h>
#include <hip/hip_bf16.h>

typedef __attribute__((ext_vector_type(8)))  short short8;
typedef __attribute__((ext_vector_type(4)))  short short4v;
typedef __attribute__((ext_vector_type(4)))  float f32x4;
typedef __attribute__((ext_vector_type(16))) float f32x16;

static __device__ inline short f2bf(float f) {
    union { __hip_bfloat16 h; unsigned short u; } cv;
    cv.h = __float2bfloat16(f);
    return (short)cv.u;
}

// ---------------------------------------------------------------------------
// Kernel 1: content [B,512,64,64] f32  ->  xT [B,64,64,512] bf16
// grid 512 = (b, h), 256 threads. LDS bounce for the transpose.
// ---------------------------------------------------------------------------
__global__ __launch_bounds__(256) void k_transpose(const float* __restrict__ x,
                                                   short* __restrict__ xT) {
    __shared__ float lds[128][65];
    int blk = blockIdx.x;
    int b = blk >> 6, h = blk & 63;
    int t = threadIdx.x;
    for (int cb = 0; cb < 4; ++cb) {
        #pragma unroll
        for (int k = 0; k < 32; ++k) {
            int idx = k * 256 + t;
            int c = idx >> 6, w = idx & 63;
            lds[c][w] = x[(((size_t)b * 512 + cb * 128 + c) * 64 + h) * 64 + w];
        }
        __syncthreads();
        #pragma unroll
        for (int k = 0; k < 32; ++k) {
            int idx = k * 256 + t;
            int w = idx >> 7, c = idx & 127;
            xT[(((size_t)b * 64 + h) * 64 + w) * 512 + cb * 128 + c] = f2bf(lds[c][w]);
        }
        __syncthreads();
    }
}

// ---------------------------------------------------------------------------
// Kernel 2: Wd_eff[b][kpos][o][i] = sum_m F1[b,o,m] * Wd[m,i,kpos]   (bf16)
// thread = (b,o,i), accumulates all 9 kpos -> dense coalesced Wd reads.
// grid 512 x 256 threads (8*32*512 = 131072 threads)
// ---------------------------------------------------------------------------
__global__ __launch_bounds__(256) void k_fold1(const float* __restrict__ f1,
                                               const float* __restrict__ wd,
                                               short* __restrict__ wd_eff) {
    int id = blockIdx.x * 256 + threadIdx.x;
    int i = id & 511;
    int o = (id >> 9) & 31;
    int b = id >> 14;
    float acc[9];
    #pragma unroll
    for (int k = 0; k < 9; ++k) acc[k] = 0.f;
    for (int m = 0; m < 32; ++m) {
        float f = f1[(b * 32 + o) * 32 + m];
        const float* wrow = wd + ((size_t)m * 512 + i) * 9;
        #pragma unroll
        for (int k = 0; k < 9; ++k) acc[k] += f * wrow[k];
    }
    #pragma unroll
    for (int k = 0; k < 9; ++k)
        wd_eff[(((size_t)b * 9 + k) * 32 + o) * 512 + i] = f2bf(acc[k]);
}

// ---------------------------------------------------------------------------
// Kernel 3: Wu_eff[b][kpos][O][c] = sum_m Wu[O,m,kpos] * F2[b,m,c]   (bf16)
// thread per output; Wu reads are wave-uniform (broadcast), F2 coalesced+L1.
// grid 4608 x 256
// ---------------------------------------------------------------------------
__global__ __launch_bounds__(256) void k_fold2(const float* __restrict__ f2,
                                               const float* __restrict__ wu,
                                               short* __restrict__ wu_eff) {
    int id = blockIdx.x * 256 + threadIdx.x;   // ((b*9+kpos)*512 + O)*32 + c
    int c = id & 31;
    int O = (id >> 5) & 511;
    int rest = id >> 14;   // b*9 + kpos
    int kpos = rest % 9;
    int b = rest / 9;
    float acc = 0.f;
    #pragma unroll
    for (int m = 0; m < 32; ++m)
        acc += wu[((size_t)O * 32 + m) * 9 + kpos] * f2[(b * 32 + m) * 32 + c];
    wu_eff[id] = f2bf(acc);
}

// ---------------------------------------------------------------------------
// Kernel 4: bd_eff[b][o] = sum_m F1[b,o,m] * bd[m]   (f32), 1 block x 256
// ---------------------------------------------------------------------------
__global__ void k_bd(const float* __restrict__ f1, const float* __restrict__ bd,
                     float* __restrict__ bd_eff) {
    int t = threadIdx.x;
    int b = t >> 5, o = t & 31;
    float acc = 0.f;
    #pragma unroll
    for (int m = 0; m < 32; ++m) acc += f1[(b * 32 + o) * 32 + m] * bd[m];
    bd_eff[t] = acc;
}

// ---------------------------------------------------------------------------
// Kernel 5: conv_down.  t[b,h,w,ch32] = LReLU( conv3x3(xT, Wd_eff) + bd_eff )
// block = (b, h): one output row.  4 waves, wave w -> pixels [16w,16w+16).
// MFMA 16x16x32 bf16, M=32 (2 tiles), weights (A) straight from global/L2,
// x tile in LDS: [3 rows][66 cols][72 ch-padded] (144 B stride = odd*16B).
// ---------------------------------------------------------------------------
__global__ __launch_bounds__(256, 2) void k_conv_down(const short* __restrict__ xT,
                                                      const short* __restrict__ wd_eff,
                                                      const float* __restrict__ bd_eff,
                                                      short* __restrict__ t_out) {
    __shared__ short xs[3 * 66 * 72];
    int blk = blockIdx.x;      // 512
    int b = blk >> 6, h = blk & 63;
    int t = threadIdx.x;
    int lane = t & 63, wave = t >> 6;
    int ntb = wave * 16;
    int lo = lane & 15, hi = lane >> 4;   // hi: 0..3 (k-group)

    // hoist bias for epilogue
    float bdv[2][4];
    #pragma unroll
    for (int mt = 0; mt < 2; ++mt)
        #pragma unroll
        for (int j = 0; j < 4; ++j)
            bdv[mt][j] = bd_eff[b * 32 + mt * 16 + hi * 4 + j];

    f32x4 acc0 = {0.f, 0.f, 0.f, 0.f};
    f32x4 acc1 = {0.f, 0.f, 0.f, 0.f};

    for (int cc = 0; cc < 8; ++cc) {       // 8 chunks of 64 input channels
        int cbase = cc * 64;
        __syncthreads();
        // stage x tile: rows h-1..h+1, cols -1..64, 64 channels (bf16)
        for (int j = t; j < 1584; j += 256) {      // 3*66*8 short8 jobs
            int pair = j >> 3, seg = j & 7;
            int r = pair / 66, col = pair % 66;
            int hin = h - 1 + r, win = col - 1;
            short8 v = {0, 0, 0, 0, 0, 0, 0, 0};
            if (hin >= 0 && hin < 64 && win >= 0 && win < 64)
                v = *(const short8*)(xT + ((size_t)((b * 64 + hin) * 64 + win)) * 512
                                        + cbase + seg * 8);
            *(short8*)(xs + (r * 66 + col) * 72 + seg * 8) = v;
        }
        __syncthreads();

        for (int kpos = 0; kpos < 9; ++kpos) {
            int kh = kpos / 3, kw = kpos % 3;
            const short* abase = wd_eff + ((size_t)(b * 9 + kpos) * 32) * 512
                                        + cbase + hi * 8;
            #pragma unroll
            for (int kt = 0; kt < 2; ++kt) {
                short8 bfrag = *(const short8*)(xs + (kh * 66 + ntb + kw + lo) * 72
                                                   + kt * 32 + hi * 8);
                short8 a0 = *(const short8*)(abase + (size_t)lo * 512 + kt * 32);
                short8 a1 = *(const short8*)(abase + (size_t)(16 + lo) * 512 + kt * 32);
                acc0 = __builtin_amdgcn_mfma_f32_16x16x32_bf16(a0, bfrag, acc0, 0, 0, 0);
                acc1 = __builtin_amdgcn_mfma_f32_16x16x32_bf16(a1, bfrag, acc1, 0, 0, 0);
            }
        }
    }

    // epilogue: D row = out-channel = mt*16 + hi*4 + j, col = pixel = ntb + lo
    int w = ntb + lo;
    size_t pixbase = ((size_t)(b * 64 + h) * 64 + w) * 32;
    #pragma unroll
    for (int mt = 0; mt < 2; ++mt) {
        f32x4 a = mt ? acc1 : acc0;
        short4v sv;
        #pragma unroll
        for (int j = 0; j < 4; ++j) {
            float v = a[j] + bdv[mt][j];
            v = v > 0.f ? v : 0.2f * v;
            sv[j] = f2bf(v);
        }
        *(short4v*)(t_out + pixbase + mt * 16 + hi * 4) = sv;
    }
}

// ---------------------------------------------------------------------------
// Kernel 6: conv_up + residual.  out = content + conv3x3(t, Wu_eff) + bu
// block = (b, 4 rows, 128 out-ch chunk). 4 waves, wave = one output row.
// MFMA 32x32x16 bf16: wave tile = 4 Mtiles x 2 Ntiles. t tile in LDS
// [6][66][40] (80 B stride = odd*16B); Wu_eff A-frags straight from L2.
// ---------------------------------------------------------------------------
__global__ __launch_bounds__(256, 2) void k_conv_up(const short* __restrict__ t_in,
                                                    const short* __restrict__ wu_eff,
                                                    const float* __restrict__ content,
                                                    const float* __restrict__ bu,
                                                    float* __restrict__ out) {
    __shared__ short tl[6 * 66 * 40];
    int blk = blockIdx.x;      // 512 = b(8) x hb(16) x oc(4)
    int oc = blk & 3;
    int hb = (blk >> 2) & 15;
    int b = blk >> 6;
    int h0 = hb * 4, Obase = oc * 128;
    int t = threadIdx.x;
    int lane = t & 63, r = t >> 6;          // r: output row within block
    int lo = lane & 31, hi = lane >> 5;     // hi: 0..1 (k-group)

    // stage t tile: rows h0-1..h0+4, cols -1..64, 32 channels
    for (int j = t; j < 1584; j += 256) {   // 6*66*4 short8 jobs
        int pair = j >> 2, seg = j & 3;
        int rr = pair / 66, col = pair % 66;
        int hin = h0 - 1 + rr, win = col - 1;
        short8 v = {0, 0, 0, 0, 0, 0, 0, 0};
        if (hin >= 0 && hin < 64 && win >= 0 && win < 64)
            v = *(const short8*)(t_in + ((size_t)((b * 64 + hin) * 64 + win)) * 32
                                      + seg * 8);
        *(short8*)(tl + (rr * 66 + col) * 40 + seg * 8) = v;
    }
    __syncthreads();

    f32x16 acc[4][2] = {};

    for (int kpos = 0; kpos < 9; ++kpos) {
        int kh = kpos / 3, kw = kpos % 3;
        #pragma unroll
        for (int kt = 0; kt < 2; ++kt) {
            short8 bfr0 = *(const short8*)(tl + ((r + kh) * 66 + 0 + kw + lo) * 40
                                              + kt * 16 + hi * 8);
            short8 bfr1 = *(const short8*)(tl + ((r + kh) * 66 + 32 + kw + lo) * 40
                                              + kt * 16 + hi * 8);
            #pragma unroll
            for (int mt = 0; mt < 4; ++mt) {
                short8 afr = *(const short8*)(wu_eff
                        + ((size_t)((b * 9 + kpos) * 512 + Obase + mt * 32 + lo)) * 32
                        + kt * 16 + hi * 8);
                acc[mt][0] = __builtin_amdgcn_mfma_f32_32x32x16_bf16(afr, bfr0, acc[mt][0], 0, 0, 0);
                acc[mt][1] = __builtin_amdgcn_mfma_f32_32x32x16_bf16(afr, bfr1, acc[mt][1], 0, 0, 0);
            }
        }
    }

    // epilogue: D row = (reg&3) + 8*(reg>>2) + 4*hi, col = nt*32 + lo
    int hrow = h0 + r;
    #pragma unroll
    for (int mt = 0; mt < 4; ++mt) {
        #pragma unroll
        for (int g = 0; g < 4; ++g) {
            f32x4 bu4 = *(const f32x4*)(bu + Obase + mt * 32 + g * 8 + hi * 4);
            #pragma unroll
            for (int jj = 0; jj < 4; ++jj) {
                int O = Obase + mt * 32 + g * 8 + hi * 4 + jj;
                int reg = g * 4 + jj;
                #pragma unroll
                for (int nt = 0; nt < 2; ++nt) {
                    int wcol = nt * 32 + lo;
                    size_t gidx = (((size_t)(b * 512 + O) * 64) + hrow) * 64 + wcol;
                    out[gidx] = acc[mt][nt][reg] + content[gidx] + bu4[jj];
                }
            }
        }
    }
}

// ---------------------------------------------------------------------------
extern "C" void kernel_launch(void* const* d_in, const int* in_sizes, int n_in,
                              void* d_out, int out_size, void* d_ws, size_t ws_size,
                              hipStream_t stream) {
    const float* content = (const float*)d_in[0];
    const float* f1      = (const float*)d_in[1];
    const float* f2      = (const float*)d_in[2];
    const float* wd      = (const float*)d_in[3];
    const float* bd      = (const float*)d_in[4];
    const float* wu      = (const float*)d_in[5];
    const float* bu      = (const float*)d_in[6];
    float* out = (float*)d_out;

    char* ws = (char*)d_ws;
    // layout: xT 32MiB | Wd_eff 2.25MiB | Wu_eff 2.25MiB | bd_eff 1KiB | t 2MiB
    short* xT     = (short*)(ws);
    short* wd_eff = (short*)(ws + 33554432);
    short* wu_eff = (short*)(ws + 35913728);
    float* bd_eff = (float*)(ws + 38273024);
    short* t_mid  = (short*)(ws + 38274048);

    k_transpose<<<dim3(512),  dim3(256), 0, stream>>>(content, xT);
    k_fold1    <<<dim3(512),  dim3(256), 0, stream>>>(f1, wd, wd_eff);
    k_fold2    <<<dim3(4608), dim3(256), 0, stream>>>(f2, wu, wu_eff);
    k_bd       <<<dim3(1),    dim3(256), 0, stream>>>(f1, bd, bd_eff);
    k_conv_down<<<dim3(512),  dim3(256), 0, stream>>>(xT, wd_eff, bd_eff, t_mid);
    k_conv_up  <<<dim3(512),  dim3(256), 0, stream>>>(t_mid, wu_eff, content, bu, out);
}

// Round 2
// 154.865 us; speedup vs baseline: 1.1888x; 1.1888x over previous
//
#include <hip/hip_runtime.h>
#include <hip/hip_bf16.h>

typedef __attribute__((ext_vector_type(8)))  short short8;
typedef __attribute__((ext_vector_type(4)))  short short4v;
typedef __attribute__((ext_vector_type(4)))  float f32x4;
typedef __attribute__((ext_vector_type(16))) float f32x16;

static __device__ inline short f2bf(float f) {
    union { __hip_bfloat16 h; unsigned short u; } cv;
    cv.h = __float2bfloat16(f);
    return (short)cv.u;
}

// ---------------------------------------------------------------------------
// Kernel 1: content [B,512,64,64] f32  ->  xT [B,64,64,512] bf16
// grid 512 = (b, h), 256 threads. LDS bounce for the transpose.
// ---------------------------------------------------------------------------
__global__ __launch_bounds__(256) void k_transpose(const float* __restrict__ x,
                                                   short* __restrict__ xT) {
    __shared__ float lds[128][65];
    int blk = blockIdx.x;
    int b = blk >> 6, h = blk & 63;
    int t = threadIdx.x;
    for (int cb = 0; cb < 4; ++cb) {
        #pragma unroll
        for (int k = 0; k < 32; ++k) {
            int idx = k * 256 + t;
            int c = idx >> 6, w = idx & 63;
            lds[c][w] = x[(((size_t)b * 512 + cb * 128 + c) * 64 + h) * 64 + w];
        }
        __syncthreads();
        #pragma unroll
        for (int k = 0; k < 32; ++k) {
            int idx = k * 256 + t;
            int w = idx >> 7, c = idx & 127;
            xT[(((size_t)b * 64 + h) * 64 + w) * 512 + cb * 128 + c] = f2bf(lds[c][w]);
        }
        __syncthreads();
    }
}

// ---------------------------------------------------------------------------
// Kernel 2: Wd_eff[b][kpos][o][i] = sum_m F1[b,o,m] * Wd[m,i,kpos]   (bf16)
// ---------------------------------------------------------------------------
__global__ __launch_bounds__(256) void k_fold1(const float* __restrict__ f1,
                                               const float* __restrict__ wd,
                                               short* __restrict__ wd_eff) {
    int id = blockIdx.x * 256 + threadIdx.x;
    int i = id & 511;
    int o = (id >> 9) & 31;
    int b = id >> 14;
    float acc[9];
    #pragma unroll
    for (int k = 0; k < 9; ++k) acc[k] = 0.f;
    for (int m = 0; m < 32; ++m) {
        float f = f1[(b * 32 + o) * 32 + m];
        const float* wrow = wd + ((size_t)m * 512 + i) * 9;
        #pragma unroll
        for (int k = 0; k < 9; ++k) acc[k] += f * wrow[k];
    }
    #pragma unroll
    for (int k = 0; k < 9; ++k)
        wd_eff[(((size_t)b * 9 + k) * 32 + o) * 512 + i] = f2bf(acc[k]);
}

// ---------------------------------------------------------------------------
// Kernel 3: Wu_eff[b][kpos][O][c] = sum_m Wu[O,m,kpos] * F2[b,m,c]   (bf16)
// ---------------------------------------------------------------------------
__global__ __launch_bounds__(256) void k_fold2(const float* __restrict__ f2,
                                               const float* __restrict__ wu,
                                               short* __restrict__ wu_eff) {
    int id = blockIdx.x * 256 + threadIdx.x;   // ((b*9+kpos)*512 + O)*32 + c
    int c = id & 31;
    int O = (id >> 5) & 511;
    int rest = id >> 14;   // b*9 + kpos
    int kpos = rest % 9;
    int b = rest / 9;
    float acc = 0.f;
    #pragma unroll
    for (int m = 0; m < 32; ++m)
        acc += wu[((size_t)O * 32 + m) * 9 + kpos] * f2[(b * 32 + m) * 32 + c];
    wu_eff[id] = f2bf(acc);
}

// ---------------------------------------------------------------------------
// Kernel 4: bd_eff[b][o] = sum_m F1[b,o,m] * bd[m]   (f32), 1 block x 256
// ---------------------------------------------------------------------------
__global__ void k_bd(const float* __restrict__ f1, const float* __restrict__ bd,
                     float* __restrict__ bd_eff) {
    int t = threadIdx.x;
    int b = t >> 5, o = t & 31;
    float acc = 0.f;
    #pragma unroll
    for (int m = 0; m < 32; ++m) acc += f1[(b * 32 + o) * 32 + m] * bd[m];
    bd_eff[t] = acc;
}

// ---------------------------------------------------------------------------
// Kernel 5a: conv_down phase 1 (K-split by 4).
// block = (b, h, s): s = group of 128 input channels (2 x 64-ch LDS chunks).
// grid 2048, 4 waves, wave w -> pixels [16w,16w+16).  MFMA 16x16x32.
// partial[b][s][px][32ch] f32, channel-contiguous f32x4 stores.
// ---------------------------------------------------------------------------
__global__ __launch_bounds__(256) void k_conv_down_p(const short* __restrict__ xT,
                                                     const short* __restrict__ wd_eff,
                                                     float* __restrict__ part) {
    __shared__ short xs[3 * 66 * 72];
    int blk = blockIdx.x;      // 2048 = b(8) x h(64) x s(4)
    int s = blk & 3;
    int h = (blk >> 2) & 63;
    int b = blk >> 8;
    int t = threadIdx.x;
    int lane = t & 63, wave = t >> 6;
    int ntb = wave * 16;
    int lo = lane & 15, hi = lane >> 4;   // hi: 0..3 (k-group)

    f32x4 acc0 = {0.f, 0.f, 0.f, 0.f};
    f32x4 acc1 = {0.f, 0.f, 0.f, 0.f};

    for (int ci = 0; ci < 2; ++ci) {       // 2 chunks of 64 input channels
        int cbase = (s * 2 + ci) * 64;
        __syncthreads();
        // stage x tile: rows h-1..h+1, cols -1..64, 64 channels (bf16)
        for (int j = t; j < 1584; j += 256) {      // 3*66*8 short8 jobs
            int pair = j >> 3, seg = j & 7;
            int r = pair / 66, col = pair % 66;
            int hin = h - 1 + r, win = col - 1;
            short8 v = {0, 0, 0, 0, 0, 0, 0, 0};
            if (hin >= 0 && hin < 64 && win >= 0 && win < 64)
                v = *(const short8*)(xT + ((size_t)((b * 64 + hin) * 64 + win)) * 512
                                        + cbase + seg * 8);
            *(short8*)(xs + (r * 66 + col) * 72 + seg * 8) = v;
        }
        __syncthreads();

        for (int kpos = 0; kpos < 9; ++kpos) {
            int kh = kpos / 3, kw = kpos % 3;
            const short* abase = wd_eff + ((size_t)(b * 9 + kpos) * 32) * 512
                                        + cbase + hi * 8;
            #pragma unroll
            for (int kt = 0; kt < 2; ++kt) {
                short8 bfrag = *(const short8*)(xs + (kh * 66 + ntb + kw + lo) * 72
                                                   + kt * 32 + hi * 8);
                short8 a0 = *(const short8*)(abase + (size_t)lo * 512 + kt * 32);
                short8 a1 = *(const short8*)(abase + (size_t)(16 + lo) * 512 + kt * 32);
                acc0 = __builtin_amdgcn_mfma_f32_16x16x32_bf16(a0, bfrag, acc0, 0, 0, 0);
                acc1 = __builtin_amdgcn_mfma_f32_16x16x32_bf16(a1, bfrag, acc1, 0, 0, 0);
            }
        }
    }

    // D: row = ch = mt*16 + hi*4 + j (j contiguous), col = px = ntb + lo
    int px = ntb + lo;
    float* pb = part + ((size_t)(b * 4 + s) * 4096 + h * 64 + px) * 32;
    *(f32x4*)(pb + hi * 4)      = acc0;
    *(f32x4*)(pb + 16 + hi * 4) = acc1;
}

// ---------------------------------------------------------------------------
// Kernel 5b: reduce 4 partials + bias, LeakyReLU, -> bf16 t_mid[b][px][32]
// thread = (b, px): 32768 threads = 128 blocks x 256.
// ---------------------------------------------------------------------------
__global__ __launch_bounds__(256) void k_down_reduce(const float* __restrict__ part,
                                                     const float* __restrict__ bd_eff,
                                                     short* __restrict__ t_mid) {
    int id = blockIdx.x * 256 + threadIdx.x;   // (b, px)
    int b = id >> 12, px = id & 4095;
    const float* p0 = part + ((size_t)(b * 4) * 4096 + px) * 32;
    const size_t sstr = (size_t)4096 * 32;
    short* o = t_mid + ((size_t)b * 4096 + px) * 32;
    #pragma unroll
    for (int cq = 0; cq < 8; ++cq) {
        f32x4 v = *(const f32x4*)(p0 + cq * 4);
        #pragma unroll
        for (int s = 1; s < 4; ++s) {
            f32x4 u = *(const f32x4*)(p0 + s * sstr + cq * 4);
            v.x += u.x; v.y += u.y; v.z += u.z; v.w += u.w;
        }
        f32x4 bd4 = *(const f32x4*)(bd_eff + b * 32 + cq * 4);
        short4v sv;
        #pragma unroll
        for (int j = 0; j < 4; ++j) {
            float f = v[j] + bd4[j];
            f = f > 0.f ? f : 0.2f * f;
            sv[j] = f2bf(f);
        }
        *(short4v*)(o + cq * 4) = sv;
    }
}

// ---------------------------------------------------------------------------
// Kernel 6: conv_up + residual.  out = content + conv3x3(t, Wu_eff) + bu
// block = (b, 4 rows, 32 out-ch chunk). grid 2048, 4 waves, wave = one row.
// MFMA 32x32x16 bf16: wave tile = 1 Mtile x 2 Ntiles. t tile in LDS
// [6][66][40] (80 B stride = odd*16B); Wu_eff A-frags straight from L2.
// ---------------------------------------------------------------------------
__global__ __launch_bounds__(256) void k_conv_up(const short* __restrict__ t_in,
                                                 const short* __restrict__ wu_eff,
                                                 const float* __restrict__ content,
                                                 const float* __restrict__ bu,
                                                 float* __restrict__ out) {
    __shared__ short tl[6 * 66 * 40];
    int blk = blockIdx.x;      // 2048 = b(8) x hb(16) x oc(16)
    int oc = blk & 15;
    int hb = (blk >> 4) & 15;
    int b = blk >> 8;
    int h0 = hb * 4, Obase = oc * 32;
    int t = threadIdx.x;
    int lane = t & 63, r = t >> 6;          // r: output row within block
    int lo = lane & 31, hi = lane >> 5;     // hi: 0..1 (k-group)

    // stage t tile: rows h0-1..h0+4, cols -1..64, 32 channels
    for (int j = t; j < 1584; j += 256) {   // 6*66*4 short8 jobs
        int pair = j >> 2, seg = j & 3;
        int rr = pair / 66, col = pair % 66;
        int hin = h0 - 1 + rr, win = col - 1;
        short8 v = {0, 0, 0, 0, 0, 0, 0, 0};
        if (hin >= 0 && hin < 64 && win >= 0 && win < 64)
            v = *(const short8*)(t_in + ((size_t)((b * 64 + hin) * 64 + win)) * 32
                                      + seg * 8);
        *(short8*)(tl + (rr * 66 + col) * 40 + seg * 8) = v;
    }
    __syncthreads();

    f32x16 acc[2] = {};

    for (int kpos = 0; kpos < 9; ++kpos) {
        int kh = kpos / 3, kw = kpos % 3;
        #pragma unroll
        for (int kt = 0; kt < 2; ++kt) {
            short8 bfr0 = *(const short8*)(tl + ((r + kh) * 66 + 0 + kw + lo) * 40
                                              + kt * 16 + hi * 8);
            short8 bfr1 = *(const short8*)(tl + ((r + kh) * 66 + 32 + kw + lo) * 40
                                              + kt * 16 + hi * 8);
            short8 afr = *(const short8*)(wu_eff
                    + ((size_t)((b * 9 + kpos) * 512 + Obase + lo)) * 32
                    + kt * 16 + hi * 8);
            acc[0] = __builtin_amdgcn_mfma_f32_32x32x16_bf16(afr, bfr0, acc[0], 0, 0, 0);
            acc[1] = __builtin_amdgcn_mfma_f32_32x32x16_bf16(afr, bfr1, acc[1], 0, 0, 0);
        }
    }

    // epilogue: D row = (reg&3) + 8*(reg>>2) + 4*hi, col = nt*32 + lo
    int hrow = h0 + r;
    #pragma unroll
    for (int g = 0; g < 4; ++g) {
        f32x4 bu4 = *(const f32x4*)(bu + Obase + g * 8 + hi * 4);
        #pragma unroll
        for (int jj = 0; jj < 4; ++jj) {
            int O = Obase + g * 8 + hi * 4 + jj;
            int reg = g * 4 + jj;
            #pragma unroll
            for (int nt = 0; nt < 2; ++nt) {
                int wcol = nt * 32 + lo;
                size_t gidx = (((size_t)(b * 512 + O) * 64) + hrow) * 64 + wcol;
                out[gidx] = acc[nt][reg] + content[gidx] + bu4[jj];
            }
        }
    }
}

// ---------------------------------------------------------------------------
extern "C" void kernel_launch(void* const* d_in, const int* in_sizes, int n_in,
                              void* d_out, int out_size, void* d_ws, size_t ws_size,
                              hipStream_t stream) {
    const float* content = (const float*)d_in[0];
    const float* f1      = (const float*)d_in[1];
    const float* f2      = (const float*)d_in[2];
    const float* wd      = (const float*)d_in[3];
    const float* bd      = (const float*)d_in[4];
    const float* wu      = (const float*)d_in[5];
    const float* bu      = (const float*)d_in[6];
    float* out = (float*)d_out;

    char* ws = (char*)d_ws;
    // layout: xT 32MiB | Wd_eff 2.25MiB | Wu_eff 2.25MiB | bd_eff 1KiB
    //         | t 2MiB | part 16MiB   (total ~54.5 MiB)
    short* xT     = (short*)(ws);
    short* wd_eff = (short*)(ws + 33554432);
    short* wu_eff = (short*)(ws + 35913728);
    float* bd_eff = (float*)(ws + 38273024);
    short* t_mid  = (short*)(ws + 38274048);
    float* part   = (float*)(ws + 40371200);

    k_transpose  <<<dim3(512),  dim3(256), 0, stream>>>(content, xT);
    k_fold1      <<<dim3(512),  dim3(256), 0, stream>>>(f1, wd, wd_eff);
    k_fold2      <<<dim3(4608), dim3(256), 0, stream>>>(f2, wu, wu_eff);
    k_bd         <<<dim3(1),    dim3(256), 0, stream>>>(f1, bd, bd_eff);
    k_conv_down_p<<<dim3(2048), dim3(256), 0, stream>>>(xT, wd_eff, part);
    k_down_reduce<<<dim3(128),  dim3(256), 0, stream>>>(part, bd_eff, t_mid);
    k_conv_up    <<<dim3(2048), dim3(256), 0, stream>>>(t_mid, wu_eff, content, bu, out);
}

// Round 3
// 147.874 us; speedup vs baseline: 1.2450x; 1.0473x over previous
//
#include <hip/hip_runtime.h>
#include <hip/hip_bf16.h>

typedef __attribute__((ext_vector_type(8)))  short short8;
typedef __attribute__((ext_vector_type(4)))  short short4v;
typedef __attribute__((ext_vector_type(4)))  float f32x4;
typedef __attribute__((ext_vector_type(16))) float f32x16;

static __device__ inline short f2bf(float f) {
    union { __hip_bfloat16 h; unsigned short u; } cv;
    cv.h = __float2bfloat16(f);
    return (short)cv.u;
}

// ---------------------------------------------------------------------------
// Kernel 1: content [B,512,64,64] f32  ->  xT [B,64,64,512] bf16
// ---------------------------------------------------------------------------
__global__ __launch_bounds__(256) void k_transpose(const float* __restrict__ x,
                                                   short* __restrict__ xT) {
    __shared__ float lds[128][65];
    int blk = blockIdx.x;
    int b = blk >> 6, h = blk & 63;
    int t = threadIdx.x;
    for (int cb = 0; cb < 4; ++cb) {
        #pragma unroll
        for (int k = 0; k < 32; ++k) {
            int idx = k * 256 + t;
            int c = idx >> 6, w = idx & 63;
            lds[c][w] = x[(((size_t)b * 512 + cb * 128 + c) * 64 + h) * 64 + w];
        }
        __syncthreads();
        #pragma unroll
        for (int k = 0; k < 32; ++k) {
            int idx = k * 256 + t;
            int w = idx >> 7, c = idx & 127;
            xT[(((size_t)b * 64 + h) * 64 + w) * 512 + cb * 128 + c] = f2bf(lds[c][w]);
        }
        __syncthreads();
    }
}

// ---------------------------------------------------------------------------
// Kernel 2: Wd_eff[b][kpos][o][i] = sum_m F1[b,o,m] * Wd[m,i,kpos]   (bf16)
// ---------------------------------------------------------------------------
__global__ __launch_bounds__(256) void k_fold1(const float* __restrict__ f1,
                                               const float* __restrict__ wd,
                                               short* __restrict__ wd_eff) {
    int id = blockIdx.x * 256 + threadIdx.x;
    int i = id & 511;
    int o = (id >> 9) & 31;
    int b = id >> 14;
    float acc[9];
    #pragma unroll
    for (int k = 0; k < 9; ++k) acc[k] = 0.f;
    for (int m = 0; m < 32; ++m) {
        float f = f1[(b * 32 + o) * 32 + m];
        const float* wrow = wd + ((size_t)m * 512 + i) * 9;
        #pragma unroll
        for (int k = 0; k < 9; ++k) acc[k] += f * wrow[k];
    }
    #pragma unroll
    for (int k = 0; k < 9; ++k)
        wd_eff[(((size_t)b * 9 + k) * 32 + o) * 512 + i] = f2bf(acc[k]);
}

// ---------------------------------------------------------------------------
// Kernel 3: Wu_eff[b][kpos][O][c] = sum_m Wu[O,m,kpos] * F2[b,m,c]   (bf16)
// ---------------------------------------------------------------------------
__global__ __launch_bounds__(256) void k_fold2(const float* __restrict__ f2,
                                               const float* __restrict__ wu,
                                               short* __restrict__ wu_eff) {
    int id = blockIdx.x * 256 + threadIdx.x;   // ((b*9+kpos)*512 + O)*32 + c
    int c = id & 31;
    int O = (id >> 5) & 511;
    int rest = id >> 14;   // b*9 + kpos
    int kpos = rest % 9;
    int b = rest / 9;
    float acc = 0.f;
    #pragma unroll
    for (int m = 0; m < 32; ++m)
        acc += wu[((size_t)O * 32 + m) * 9 + kpos] * f2[(b * 32 + m) * 32 + c];
    wu_eff[id] = f2bf(acc);
}

// ---------------------------------------------------------------------------
// Kernel 4: bd_eff[b][o] = sum_m F1[b,o,m] * bd[m]; also zero the 1 KiB
// zero-page used by conv_down's predicated B loads.
// ---------------------------------------------------------------------------
__global__ void k_bd(const float* __restrict__ f1, const float* __restrict__ bd,
                     float* __restrict__ bd_eff, float* __restrict__ zp) {
    int t = threadIdx.x;
    zp[t] = 0.f;                 // 256 x 4B = 1 KiB zero page
    int b = t >> 5, o = t & 31;
    float acc = 0.f;
    #pragma unroll
    for (int m = 0; m < 32; ++m) acc += f1[(b * 32 + o) * 32 + m] * bd[m];
    bd_eff[t] = acc;
}

// ---------------------------------------------------------------------------
// Kernel 5a: conv_down phase 1 — barrier-free, LDS-free direct GEMM.
// wave = (b, s: 128-ch chunk, 32-px group). grid 1024 x 256 (4 waves/block,
// wave w -> s=w). 9 kpos x 4 ksteps fully unrolled; A from L2-resident
// wd_eff, B straight from xT with zero-page address predication.
// partial[b][s][px][32ch] f32.
// ---------------------------------------------------------------------------
__global__ __launch_bounds__(256, 4) void k_conv_down_p(const short* __restrict__ xT,
                                                        const short* __restrict__ wd_eff,
                                                        const short* __restrict__ zpage,
                                                        float* __restrict__ part) {
    int blk = blockIdx.x;          // 1024 = b(8) x pxg(128)
    int b = blk >> 7;
    int pxg = blk & 127;
    int h = pxg >> 1, w0 = (pxg & 1) * 32;
    int t = threadIdx.x;
    int lane = t & 63, s = t >> 6;             // s: channel chunk 0..3
    int lo = lane & 15, hi = lane >> 4;        // MFMA 16x16x32 lane split

    const int cb0 = s * 128;                   // this wave's channel base

    f32x4 acc[2][2] = {};                      // [Mtile][Ntile]

    #pragma unroll
    for (int kpos = 0; kpos < 9; ++kpos) {
        const int kh = kpos / 3, kw = kpos % 3;
        int hq = h + kh - 1;
        if (hq >= 0 && hq < 64) {              // wave-uniform branch
            // A base: row = lo (+16 for Mtile1), ch = cb0 + hi*8 (+kt*32)
            const short* ap = wd_eff + ((size_t)((b * 9 + kpos) * 32 + lo)) * 512
                                     + cb0 + hi * 8;
            // B bases per Ntile: pixel col = w0 + nt*16 + lo + kw - 1
            const short* bp[2];
            #pragma unroll
            for (int nt = 0; nt < 2; ++nt) {
                int wp = w0 + nt * 16 + lo + kw - 1;
                const short* real = xT + ((size_t)((b * 64 + hq) * 64 + wp)) * 512
                                       + cb0 + hi * 8;
                bp[nt] = ((unsigned)wp < 64u) ? real : zpage;
            }
            #pragma unroll
            for (int kt = 0; kt < 4; ++kt) {
                short8 a0 = *(const short8*)(ap + kt * 32);
                short8 a1 = *(const short8*)(ap + 8192 + kt * 32);
                short8 b0 = *(const short8*)(bp[0] + kt * 32);
                short8 b1 = *(const short8*)(bp[1] + kt * 32);
                acc[0][0] = __builtin_amdgcn_mfma_f32_16x16x32_bf16(a0, b0, acc[0][0], 0, 0, 0);
                acc[0][1] = __builtin_amdgcn_mfma_f32_16x16x32_bf16(a0, b1, acc[0][1], 0, 0, 0);
                acc[1][0] = __builtin_amdgcn_mfma_f32_16x16x32_bf16(a1, b0, acc[1][0], 0, 0, 0);
                acc[1][1] = __builtin_amdgcn_mfma_f32_16x16x32_bf16(a1, b1, acc[1][1], 0, 0, 0);
            }
        }
    }

    // D: col = px-in-tile = lo, row = ch = mt*16 + hi*4 + j
    #pragma unroll
    for (int nt = 0; nt < 2; ++nt) {
        int px = h * 64 + w0 + nt * 16 + lo;
        float* pb = part + ((size_t)(b * 4 + s) * 4096 + px) * 32;
        *(f32x4*)(pb + hi * 4)      = acc[0][nt];
        *(f32x4*)(pb + 16 + hi * 4) = acc[1][nt];
    }
}

// ---------------------------------------------------------------------------
// Kernel 5b: reduce 4 partials + bias, LeakyReLU, -> bf16 t_mid[b][px][32]
// ---------------------------------------------------------------------------
__global__ __launch_bounds__(256) void k_down_reduce(const float* __restrict__ part,
                                                     const float* __restrict__ bd_eff,
                                                     short* __restrict__ t_mid) {
    int id = blockIdx.x * 256 + threadIdx.x;   // (b, px)
    int b = id >> 12, px = id & 4095;
    const float* p0 = part + ((size_t)(b * 4) * 4096 + px) * 32;
    const size_t sstr = (size_t)4096 * 32;
    short* o = t_mid + ((size_t)b * 4096 + px) * 32;
    #pragma unroll
    for (int cq = 0; cq < 8; ++cq) {
        f32x4 v = *(const f32x4*)(p0 + cq * 4);
        #pragma unroll
        for (int s = 1; s < 4; ++s) {
            f32x4 u = *(const f32x4*)(p0 + s * sstr + cq * 4);
            v.x += u.x; v.y += u.y; v.z += u.z; v.w += u.w;
        }
        f32x4 bd4 = *(const f32x4*)(bd_eff + b * 32 + cq * 4);
        short4v sv;
        #pragma unroll
        for (int j = 0; j < 4; ++j) {
            float f = v[j] + bd4[j];
            f = f > 0.f ? f : 0.2f * f;
            sv[j] = f2bf(f);
        }
        *(short4v*)(o + cq * 4) = sv;
    }
}

// ---------------------------------------------------------------------------
// Kernel 6: conv_up + residual.  out = content + conv3x3(t, Wu_eff) + bu
// block = (b, 4 rows, 32 out-ch chunk). grid 2048, 4 waves, wave = one row.
// ---------------------------------------------------------------------------
__global__ __launch_bounds__(256) void k_conv_up(const short* __restrict__ t_in,
                                                 const short* __restrict__ wu_eff,
                                                 const float* __restrict__ content,
                                                 const float* __restrict__ bu,
                                                 float* __restrict__ out) {
    __shared__ short tl[6 * 66 * 40];
    int blk = blockIdx.x;      // 2048 = b(8) x hb(16) x oc(16)
    int oc = blk & 15;
    int hb = (blk >> 4) & 15;
    int b = blk >> 8;
    int h0 = hb * 4, Obase = oc * 32;
    int t = threadIdx.x;
    int lane = t & 63, r = t >> 6;          // r: output row within block
    int lo = lane & 31, hi = lane >> 5;     // hi: 0..1 (k-group)

    // stage t tile: rows h0-1..h0+4, cols -1..64, 32 channels
    for (int j = t; j < 1584; j += 256) {   // 6*66*4 short8 jobs
        int pair = j >> 2, seg = j & 3;
        int rr = pair / 66, col = pair % 66;
        int hin = h0 - 1 + rr, win = col - 1;
        short8 v = {0, 0, 0, 0, 0, 0, 0, 0};
        if (hin >= 0 && hin < 64 && win >= 0 && win < 64)
            v = *(const short8*)(t_in + ((size_t)((b * 64 + hin) * 64 + win)) * 32
                                      + seg * 8);
        *(short8*)(tl + (rr * 66 + col) * 40 + seg * 8) = v;
    }
    __syncthreads();

    f32x16 acc[2] = {};

    #pragma unroll
    for (int kpos = 0; kpos < 9; ++kpos) {
        const int kh = kpos / 3, kw = kpos % 3;
        #pragma unroll
        for (int kt = 0; kt < 2; ++kt) {
            short8 bfr0 = *(const short8*)(tl + ((r + kh) * 66 + 0 + kw + lo) * 40
                                              + kt * 16 + hi * 8);
            short8 bfr1 = *(const short8*)(tl + ((r + kh) * 66 + 32 + kw + lo) * 40
                                              + kt * 16 + hi * 8);
            short8 afr = *(const short8*)(wu_eff
                    + ((size_t)((b * 9 + kpos) * 512 + Obase + lo)) * 32
                    + kt * 16 + hi * 8);
            acc[0] = __builtin_amdgcn_mfma_f32_32x32x16_bf16(afr, bfr0, acc[0], 0, 0, 0);
            acc[1] = __builtin_amdgcn_mfma_f32_32x32x16_bf16(afr, bfr1, acc[1], 0, 0, 0);
        }
    }

    // epilogue: D row = (reg&3) + 8*(reg>>2) + 4*hi, col = nt*32 + lo
    int hrow = h0 + r;
    #pragma unroll
    for (int g = 0; g < 4; ++g) {
        f32x4 bu4 = *(const f32x4*)(bu + Obase + g * 8 + hi * 4);
        #pragma unroll
        for (int jj = 0; jj < 4; ++jj) {
            int O = Obase + g * 8 + hi * 4 + jj;
            int reg = g * 4 + jj;
            #pragma unroll
            for (int nt = 0; nt < 2; ++nt) {
                int wcol = nt * 32 + lo;
                size_t gidx = (((size_t)(b * 512 + O) * 64) + hrow) * 64 + wcol;
                out[gidx] = acc[nt][reg] + content[gidx] + bu4[jj];
            }
        }
    }
}

// ---------------------------------------------------------------------------
extern "C" void kernel_launch(void* const* d_in, const int* in_sizes, int n_in,
                              void* d_out, int out_size, void* d_ws, size_t ws_size,
                              hipStream_t stream) {
    const float* content = (const float*)d_in[0];
    const float* f1      = (const float*)d_in[1];
    const float* f2      = (const float*)d_in[2];
    const float* wd      = (const float*)d_in[3];
    const float* bd      = (const float*)d_in[4];
    const float* wu      = (const float*)d_in[5];
    const float* bu      = (const float*)d_in[6];
    float* out = (float*)d_out;

    char* ws = (char*)d_ws;
    // layout: zp 4KiB | xT 32MiB | Wd_eff 2.25MiB | Wu_eff 2.25MiB |
    //         bd_eff 1KiB | t 2MiB | part 16MiB   (total ~54.5 MiB)
    float* zp     = (float*)(ws);
    short* xT     = (short*)(ws + 4096);
    short* wd_eff = (short*)(ws + 33558528);
    short* wu_eff = (short*)(ws + 35917824);
    float* bd_eff = (float*)(ws + 38277120);
    short* t_mid  = (short*)(ws + 38278144);
    float* part   = (float*)(ws + 40375296);

    k_transpose  <<<dim3(512),  dim3(256), 0, stream>>>(content, xT);
    k_fold1      <<<dim3(512),  dim3(256), 0, stream>>>(f1, wd, wd_eff);
    k_fold2      <<<dim3(4608), dim3(256), 0, stream>>>(f2, wu, wu_eff);
    k_bd         <<<dim3(1),    dim3(256), 0, stream>>>(f1, bd, bd_eff, zp);
    k_conv_down_p<<<dim3(1024), dim3(256), 0, stream>>>(xT, wd_eff, (const short*)zp, part);
    k_down_reduce<<<dim3(128),  dim3(256), 0, stream>>>(part, bd_eff, t_mid);
    k_conv_up    <<<dim3(2048), dim3(256), 0, stream>>>(t_mid, wu_eff, content, bu, out);
}